// Round 13
// baseline (69.683 us; speedup 1.0000x reference)
//
#include <hip/hip_runtime.h>
#include <hip/hip_bf16.h>

#define NN 2048
#define DD 128

typedef __attribute__((ext_vector_type(4))) float f32x4;
typedef __attribute__((ext_vector_type(8))) short short8;

__device__ __forceinline__ unsigned short f2bf_bits(float f) {
  union { __hip_bfloat16 h; unsigned short s; } u;
  u.h = __float2bfloat16(f);
  return u.s;
}

__device__ __forceinline__ short8 cvt8(f32x4 a, f32x4 b) {
  short8 r;
  r[0] = (short)f2bf_bits(a[0]); r[1] = (short)f2bf_bits(a[1]);
  r[2] = (short)f2bf_bits(a[2]); r[3] = (short)f2bf_bits(a[3]);
  r[4] = (short)f2bf_bits(b[0]); r[5] = (short)f2bf_bits(b[1]);
  r[6] = (short)f2bf_bits(b[2]); r[7] = (short)f2bf_bits(b[3]);
  return r;
}

__device__ __forceinline__ void gld16(const void* src, void* lds) {
  __builtin_amdgcn_global_load_lds(
      (const __attribute__((address_space(1))) void*)src,
      (__attribute__((address_space(3))) void*)lds, 16, 0, 0);
}

// ---------- K1: dnorm = rsqrt(rowsum(adj)+1e-8) (pure read, ~21 µs) ----------
__global__ void k_degree(const float* __restrict__ adj, float* __restrict__ dnorm) {
  const int wv = threadIdx.x >> 6;
  const int ln = threadIdx.x & 63;
  const int row = blockIdx.x * 4 + wv;
  const f32x4* rowp = (const f32x4*)(adj + (size_t)row * NN);
  float s = 0.0f;
#pragma unroll
  for (int i = 0; i < 8; ++i) {
    f32x4 v = rowp[i * 64 + ln];
    s += v[0] + v[1] + v[2] + v[3];
  }
#pragma unroll
  for (int off = 32; off >= 1; off >>= 1) s += __shfl_xor(s, off);
  if (ln == 0) dnorm[row] = rsqrtf(s + 1e-8f);
}

// ---------- K2: yT[b][d][n] = bf16(dnorm[n] * (x@W)[n][d]) (proven) ----------
__global__ void k_y(const float* __restrict__ x, const float* __restrict__ W,
                    const float* __restrict__ dnorm, short* __restrict__ yT) {
  const int ln = threadIdx.x & 63;
  const int wv = threadIdx.x >> 6;
  const int bb = blockIdx.x >> 5;
  const int n0 = (blockIdx.x & 31) << 6;
  const int l15 = ln & 15, l4 = ln >> 4;
  const int dbase = wv * 32;

  short8 af[2][4];
#pragma unroll
  for (int dt = 0; dt < 2; ++dt)
#pragma unroll
    for (int ks = 0; ks < 4; ++ks) {
      short8 a;
#pragma unroll
      for (int j = 0; j < 8; ++j)
        a[j] = (short)f2bf_bits(W[(size_t)(ks * 32 + l4 * 8 + j) * DD + dbase + dt * 16 + l15]);
      af[dt][ks] = a;
    }

  f32x4 acc[2][4];
#pragma unroll
  for (int dt = 0; dt < 2; ++dt)
#pragma unroll
    for (int nt = 0; nt < 4; ++nt) acc[dt][nt] = (f32x4)0.0f;

  const float* xb = x + (size_t)bb * NN * DD;
  const float* dnb = dnorm + (size_t)bb * NN;
#pragma unroll
  for (int nt = 0; nt < 4; ++nt) {
    const int n = n0 + nt * 16 + l15;
    const float dn = dnb[n];
#pragma unroll
    for (int ks = 0; ks < 4; ++ks) {
      f32x4 p = *(const f32x4*)(xb + (size_t)n * DD + ks * 32 + l4 * 8);
      f32x4 q = *(const f32x4*)(xb + (size_t)n * DD + ks * 32 + l4 * 8 + 4);
      short8 bf = cvt8(p * dn, q * dn);
#pragma unroll
      for (int dt = 0; dt < 2; ++dt)
        acc[dt][nt] = __builtin_amdgcn_mfma_f32_16x16x32_bf16(af[dt][ks], bf, acc[dt][nt], 0, 0, 0);
    }
  }

  short* yb = yT + (size_t)bb * DD * NN;
#pragma unroll
  for (int dt = 0; dt < 2; ++dt)
#pragma unroll
    for (int nt = 0; nt < 4; ++nt)
#pragma unroll
      for (int rr = 0; rr < 4; ++rr) {
        int d = dbase + dt * 16 + l4 * 4 + rr;
        yb[(size_t)d * NN + n0 + nt * 16 + l15] = (short)f2bf_bits(acc[dt][nt][rr]);
      }
}

// ---------- K3: out = dnorm_row * (adj @ y) + b ----------
// r12 structure with the vmcnt fix: B prefetch depth 2 -> 4 so the compiler's
// auto-inserted wait before B-use lands at ~vmcnt(12+) instead of vmcnt(4-6)
// (which was draining the staging queue to depth ~1 every iteration — the
// ~20 µs byte-independent fixed cost isolated across r2/r7/r11/r12).
// NBUF=4, stage lead 3, B lead 4, 4 VMEM ops/iter [S,S,B,B]:
//   at end-of-iter wait, ops after stage(T) = 10 -> vmcnt(10) exactly
//   retires stage(T); B(T) at depth 13-14 already retired.
__launch_bounds__(512, 1)
__global__ void k_gemm2(const float* __restrict__ adj, const short* __restrict__ yT,
                        const float* __restrict__ dnorm, const float* __restrict__ bias,
                        float* __restrict__ out) {
  __shared__ float As[4][4096];  // 4 x 16 KB: [64 rows][64 k] f32, 256 B rows

  const int t = threadIdx.x;
  const int ln = t & 63;
  const int wv = t >> 6;
  const int orig = ((blockIdx.x & 7) << 5) | (blockIdx.x >> 3);  // XCD-bijective, 256
  const int bb = orig >> 5;
  const int m0 = (orig & 31) << 6;

  const char* ablk = (const char*)(adj + ((size_t)bb * NN + m0) * NN);
  const int oc = (wv << 4) + (ln & 15);
  const int kg8 = (ln >> 4) << 3;
  const short* ybase = yT + ((size_t)bb * DD + oc) * NN;

  f32x4 acc[4];
#pragma unroll
  for (int m = 0; m < 4; ++m) acc[m] = (f32x4)0.0f;

  auto stage = [&](int tile, int buf) {
#pragma unroll
    for (int j = 0; j < 2; ++j) {
      unsigned L = ((unsigned)j << 13) + ((unsigned)t << 4);  // 0..16368
      unsigned row = L >> 8;
      unsigned off = L & 255u;
      unsigned soff = off ^ ((row & 7u) << 4);
      const char* src = ablk + (size_t)row * (NN * 4) + (size_t)tile * 256 + soff;
      gld16(src, (char*)As + buf * 16384 + L);
    }
  };
  auto loadB = [&](int tile, int ks) -> short8 {
    return *(const short8*)(ybase + (tile << 6) + ks * 32 + kg8);
  };
  auto compute = [&](int buf, short8 b0, short8 b1) {
    const char* base = (const char*)As + buf * 16384;
#pragma unroll
    for (int ks = 0; ks < 2; ++ks) {
      short8 bf = ks ? b1 : b0;
#pragma unroll
      for (int m = 0; m < 4; ++m) {
        unsigned row = (unsigned)(m * 16 + (ln & 15));
        unsigned c = (unsigned)(ks * 128 + (ln >> 4) * 32);
        unsigned sw = (row & 7u) << 4;
        f32x4 f0 = *(const f32x4*)(base + (row << 8) + (c ^ sw));
        f32x4 f1 = *(const f32x4*)(base + (row << 8) + ((c + 16) ^ sw));
        acc[m] = __builtin_amdgcn_mfma_f32_16x16x32_bf16(cvt8(f0, f1), bf, acc[m], 0, 0, 0);
      }
    }
  };

  // prologue: tiles 0..2 staged; B pairs for tiles 0..3; full drain once.
  stage(0, 0); stage(1, 1); stage(2, 2);
  short8 p0k0 = loadB(0, 0), p0k1 = loadB(0, 1);
  short8 p1k0 = loadB(1, 0), p1k1 = loadB(1, 1);
  short8 p2k0 = loadB(2, 0), p2k1 = loadB(2, 1);
  short8 p3k0 = loadB(3, 0), p3k1 = loadB(3, 1);
  asm volatile("s_waitcnt vmcnt(0)\n\ts_barrier" ::: "memory");

  // GITER(T): issue stage(T+3) + loadB(T+4); compute(T); vmcnt(10)+barrier;
  // commit B temps into pair slot T&3 (consumed at tile T+4).
#define GITER(T, PK0, PK1)                                              \
  {                                                                     \
    stage(((T) + 3) & 31, ((T) + 3) & 3);                               \
    short8 nb0 = loadB(((T) + 4) & 31, 0);                              \
    short8 nb1 = loadB(((T) + 4) & 31, 1);                              \
    compute((T) & 3, PK0, PK1);                                         \
    asm volatile("s_waitcnt vmcnt(10)\n\ts_barrier" ::: "memory");      \
    PK0 = nb0; PK1 = nb1;                                               \
  }

#pragma unroll 1
  for (int t4 = 0; t4 < 32; t4 += 4) {
    GITER(t4 + 0, p0k0, p0k1);
    GITER(t4 + 1, p1k0, p1k1);
    GITER(t4 + 2, p2k0, p2k1);
    GITER(t4 + 3, p3k0, p3k1);
  }
#undef GITER

  // epilogue: out = dnorm_row * acc + bias
  const float bv = bias[oc];
  const int rbase = (ln >> 4) << 2;
#pragma unroll
  for (int m = 0; m < 4; ++m) {
    f32x4 dn = *(const f32x4*)(dnorm + (size_t)bb * NN + m0 + m * 16 + rbase);
#pragma unroll
    for (int rr = 0; rr < 4; ++rr)
      out[(size_t)(bb * NN + m0 + m * 16 + rbase + rr) * DD + oc] = acc[m][rr] * dn[rr] + bv;
  }
}

extern "C" void kernel_launch(void* const* d_in, const int* in_sizes, int n_in,
                              void* d_out, int out_size, void* d_ws, size_t ws_size,
                              hipStream_t stream) {
  (void)in_sizes; (void)n_in; (void)out_size; (void)ws_size;
  const float* x = (const float*)d_in[0];
  const float* adj = (const float*)d_in[1];
  const float* W = (const float*)d_in[2];
  const float* bias = (const float*)d_in[3];
  float* out = (float*)d_out;

  char* ws = (char*)d_ws;
  float* dnorm = (float*)ws;             // 64 KB
  short* yT = (short*)(ws + (1 << 16));  // 4 MB

  k_degree<<<4096, 256, 0, stream>>>(adj, dnorm);
  k_y<<<256, 256, 0, stream>>>(x, W, dnorm, yT);
  k_gemm2<<<256, 512, 0, stream>>>(adj, yT, dnorm, bias, out);
}